// Round 7
// baseline (15821.632 us; speedup 1.0000x reference)
//
#include <hip/hip_runtime.h>
#include <hip/hip_bf16.h>

#define B_ 256
#define T_ 512
#define F_ 8
#define H_ 512
#define OUT_ 96

// 16 batch-clusters x (8 workgroups x 4 waves). Each wave owns 16 h-cols
// (48 gate-cols), W slice register-resident. 128 blocks of 256 thr =>
// co-residency guaranteed by capacity. bid stride 16 => cluster's wgs land on
// one XCD under round-robin (not assumed: semantic probe + sc1 fallback).
#define NCL 16
#define BT 16
#define NWG 8

typedef __attribute__((ext_vector_type(8))) short short8;
typedef __attribute__((ext_vector_type(4))) float f32x4;
typedef __attribute__((ext_vector_type(4))) unsigned u32x4;

// g_hbuf: [buf][chunk=col>>3][row][2 u64]  (16B = 8 bf16 cols per (chunk,row))
__device__ unsigned long long g_hbuf[2ull * 64 * 256 * 2];
// per-cluster flag block: 8 u32 packed in one 64B line
__device__ __align__(64) unsigned g_flag[NCL * 16];
// probe state
__device__ unsigned g_probe[NCL * NWG * 2 * 16];          // per-wg, per-iter 64B
__device__ __align__(64) unsigned g_pflag[NCL * NWG * 16]; // per-wg own line
__device__ unsigned g_vote[NCL * NWG];

__device__ __forceinline__ short f2bf(float v) {
  __hip_bfloat16 b = __float2bfloat16(v);
  unsigned short u;
  __builtin_memcpy(&u, &b, 2);
  return (short)u;
}

__device__ __forceinline__ size_t hidx(int buf, int chunk, int row) {
  return ((size_t)((buf * 64 + chunk) * 256 + row)) * 2;
}

__device__ __forceinline__ unsigned ld_sc0(const unsigned* p) {
  unsigned v;
  asm volatile("global_load_dword %0, %1, off sc0\n\ts_waitcnt vmcnt(0)"
               : "=&v"(v) : "v"(p) : "memory");
  return v;
}
__device__ __forceinline__ void st_sc0(unsigned* p, unsigned v) {
  asm volatile("global_store_dword %0, %1, off sc0" :: "v"(p), "v"(v) : "memory");
}
__device__ __forceinline__ void st64_sc0(unsigned long long* p, unsigned long long v) {
  asm volatile("global_store_dwordx2 %0, %1, off sc0" :: "v"(p), "v"(v) : "memory");
}
__device__ __forceinline__ unsigned probeval(int i, int j, int k) {
  return 0xA5000000u ^ ((unsigned)i << 16) ^ ((unsigned)j << 8) ^ (unsigned)k;
}

__global__ void init_state() {
  int i = blockIdx.x * 256 + (int)threadIdx.x;
  if (i < NCL * 16) g_flag[i] = 0;
  if (i < NCL * NWG * 2 * 16) g_probe[i] = 0;
  if (i < NCL * NWG * 16) g_pflag[i] = 0;
  if (i < NCL * NWG) g_vote[i] = 0;
}

template <bool FAST>
__device__ __forceinline__ void run_gru(
    const float* x, const float* w_ih, const float* w_hh,
    const float* bias_ih, const float* bias_hh,
    const float* fc_w, const float* fc_b, float* out,
    int tid, int w, int lane, int l15, int lg, int cl, int wgj, int rb0, int c0,
    short8* h_lds, short (*t_h)[68]) {
  // ---- W fragments, register-resident for all 512 steps ----
  short8 wfrag[3][17];
#pragma unroll
  for (int g = 0; g < 3; ++g) {
    const float* wr = w_hh + (size_t)(g * H_ + c0 + l15) * H_ + lg * 8;
#pragma unroll
    for (int kk = 0; kk < 16; ++kk) {
      f32x4 a = ((const f32x4*)(wr + kk * 32))[0];
      f32x4 b2 = ((const f32x4*)(wr + kk * 32))[1];
      short8 o;
#pragma unroll
      for (int j = 0; j < 4; ++j) { o[j] = f2bf(a[j]); o[4 + j] = f2bf(b2[j]); }
      wfrag[g][kk] = o;
    }
    short8 o = {0, 0, 0, 0, 0, 0, 0, 0};
    if (lg == 0) {  // k = 512..519 -> W_ih row
      const f32x4* wi = (const f32x4*)(w_ih + (size_t)(g * H_ + c0 + l15) * F_);
      f32x4 a = wi[0], b2 = wi[1];
#pragma unroll
      for (int j = 0; j < 4; ++j) { o[j] = f2bf(a[j]); o[4 + j] = f2bf(b2[j]); }
    }
    wfrag[g][16] = o;
  }

  const int colh = c0 + l15;
  const float b_r = bias_ih[colh] + bias_hh[colh];
  const float b_z = bias_ih[H_ + colh] + bias_hh[H_ + colh];
  const float bin_ = bias_ih[2 * H_ + colh];
  const float bhn_ = bias_hh[2 * H_ + colh];

  float hown[4] = {0.f, 0.f, 0.f, 0.f};
  bool gaveup = false;
  const int hrow = rb0 + l15;
  const float* xrow = x + (size_t)hrow * T_ * F_;

  f32x4 xa = ((const f32x4*)xrow)[0];
  f32x4 xb2 = ((const f32x4*)xrow)[1];

  for (int t = 0; t < T_; ++t) {
    if (t > 0) {
      // ---- poll packed flag line: one load per lane, __all exit ----
      if (!gaveup) {
        unsigned spins = 0;
        for (;;) {
          unsigned f;
          if (FAST) {
            f = ld_sc0(&g_flag[cl * 16 + (lane & 7)]);
          } else {
            f = __hip_atomic_load(&g_flag[cl * 16 + (lane & 7)], __ATOMIC_RELAXED,
                                  __HIP_MEMORY_SCOPE_AGENT);
          }
          if (__all((int)(f >= (unsigned)t))) break;
          if (!FAST) __builtin_amdgcn_s_sleep(1);
          if (++spins > (1u << 20)) { gaveup = true; break; }
        }
        if (!FAST) __builtin_amdgcn_fence(__ATOMIC_ACQUIRE, "agent");
      }
      // ---- cooperative gather -> LDS (lane-linear, conflict-free) ----
      if (FAST) {
        const char* hb = (const char*)g_hbuf + (size_t)(t & 1) * 262144;
        const char* p0 = hb + (tid >> 4) * 4096 + (rb0 + (tid & 15)) * 16;
        u32x4 g0, g1, g2, g3;
        asm volatile(
            "global_load_dwordx4 %0, %4, off sc0\n\t"
            "global_load_dwordx4 %1, %5, off sc0\n\t"
            "global_load_dwordx4 %2, %6, off sc0\n\t"
            "global_load_dwordx4 %3, %7, off sc0\n\t"
            "s_waitcnt vmcnt(0)"
            : "=&v"(g0), "=&v"(g1), "=&v"(g2), "=&v"(g3)
            : "v"(p0), "v"(p0 + 65536), "v"(p0 + 131072), "v"(p0 + 196608)
            : "memory");
        union { u32x4 u; short8 s; } c0u = {g0}, c1u = {g1}, c2u = {g2}, c3u = {g3};
        h_lds[tid] = c0u.s;
        h_lds[tid + 256] = c1u.s;
        h_lds[tid + 512] = c2u.s;
        h_lds[tid + 768] = c3u.s;
      } else {
        const int buf = t & 1;
#pragma unroll
        for (int r4 = 0; r4 < 4; ++r4) {
          const int idx = r4 * 256 + tid;
          size_t i0 = hidx(buf, idx >> 4, rb0 + (idx & 15));
          unsigned long long q0 = __hip_atomic_load(&g_hbuf[i0], __ATOMIC_RELAXED,
                                                    __HIP_MEMORY_SCOPE_AGENT);
          unsigned long long q1 = __hip_atomic_load(&g_hbuf[i0 + 1], __ATOMIC_RELAXED,
                                                    __HIP_MEMORY_SCOPE_AGENT);
          union { unsigned long long q[2]; short8 s; } u;
          u.q[0] = q0; u.q[1] = q1;
          h_lds[idx] = u.s;
        }
      }
    }

    short8 xf;
#pragma unroll
    for (int j = 0; j < 4; ++j) { xf[j] = f2bf(xa[j]); xf[4 + j] = f2bf(xb2[j]); }

    __syncthreads();  // h_lds ready

    {
      const int tn = (t + 1 < T_) ? t + 1 : T_ - 1;
      xa = ((const f32x4*)(xrow + (size_t)tn * F_))[0];
      xb2 = ((const f32x4*)(xrow + (size_t)tn * F_))[1];
    }

    // ---- 51 MFMAs ----
    f32x4 acc_r = {0.f, 0.f, 0.f, 0.f}, acc_z = {0.f, 0.f, 0.f, 0.f};
    f32x4 acc_nh = {0.f, 0.f, 0.f, 0.f}, acc_nx = {0.f, 0.f, 0.f, 0.f};
    if (t > 0) {
#pragma unroll
      for (int kk = 0; kk < 16; ++kk) {
        short8 a = h_lds[(kk * 4 + lg) * 16 + l15];
        acc_r = __builtin_amdgcn_mfma_f32_16x16x32_bf16(a, wfrag[0][kk], acc_r, 0, 0, 0);
        acc_z = __builtin_amdgcn_mfma_f32_16x16x32_bf16(a, wfrag[1][kk], acc_z, 0, 0, 0);
        acc_nh = __builtin_amdgcn_mfma_f32_16x16x32_bf16(a, wfrag[2][kk], acc_nh, 0, 0, 0);
      }
    }
    acc_r = __builtin_amdgcn_mfma_f32_16x16x32_bf16(xf, wfrag[0][16], acc_r, 0, 0, 0);
    acc_z = __builtin_amdgcn_mfma_f32_16x16x32_bf16(xf, wfrag[1][16], acc_z, 0, 0, 0);
    acc_nx = __builtin_amdgcn_mfma_f32_16x16x32_bf16(xf, wfrag[2][16], acc_nx, 0, 0, 0);

    // ---- gates + fp32-carry state update ----
    short hnew[4];
#pragma unroll
    for (int q = 0; q < 4; ++q) {
      float pr = acc_r[q] + b_r;
      float pz = acc_z[q] + b_z;
      float r = 1.f / (1.f + __expf(-pr));
      float z = 1.f / (1.f + __expf(-pz));
      float n = tanhf(acc_nx[q] + bin_ + r * (acc_nh[q] + bhn_));
      hown[q] = n + z * (hown[q] - n);
      hnew[q] = f2bf(hown[q]);
    }

    // ---- publish via padded LDS transpose -> one u64 store per lane ----
#pragma unroll
    for (int q = 0; q < 4; ++q) t_h[4 * lg + q][w * 16 + l15] = hnew[q];
    __syncthreads();  // tile complete
    {
      const int row_l = tid >> 4;
      const int ucol = tid & 15;
      const int col = wgj * 64 + ucol * 4;
      const int grow = rb0 + row_l;
      unsigned long long v;
      __builtin_memcpy(&v, &t_h[row_l][ucol * 4], 8);
      size_t i0 = hidx((t + 1) & 1, col >> 3, grow) + ((col >> 2) & 1);
      if (FAST) {
        st64_sc0(&g_hbuf[i0], v);
        asm volatile("s_waitcnt vmcnt(0)" ::: "memory");  // asm stores invisible to barrier drain
      } else {
        __hip_atomic_store(&g_hbuf[i0], v, __ATOMIC_RELAXED, __HIP_MEMORY_SCOPE_AGENT);
      }
    }
    __syncthreads();  // all waves' publishes drained
    if (tid == 0) {
      if (FAST) st_sc0(&g_flag[cl * 16 + wgj], (unsigned)(t + 1));
      else __hip_atomic_store(&g_flag[cl * 16 + wgj], (unsigned)(t + 1),
                              __ATOMIC_RELAXED, __HIP_MEMORY_SCOPE_AGENT);
    }
  }

  // ---- final FC: 6 waves per cluster cover the 96 output columns ----
  const int wi = wgj * 4 + w;
  if (wi >= OUT_ / 16) return;
  if (!gaveup) {
    unsigned spins = 0;
    for (;;) {
      unsigned f;
      if (FAST) f = ld_sc0(&g_flag[cl * 16 + (lane & 7)]);
      else f = __hip_atomic_load(&g_flag[cl * 16 + (lane & 7)], __ATOMIC_RELAXED,
                                 __HIP_MEMORY_SCOPE_AGENT);
      if (__all((int)(f >= (unsigned)T_))) break;
      if (!FAST) __builtin_amdgcn_s_sleep(1);
      if (++spins > (1u << 20)) break;
    }
    if (!FAST) __builtin_amdgcn_fence(__ATOMIC_ACQUIRE, "agent");
  }
  short8 afrag[16];
  const int hrow2 = rb0 + l15;
  if (FAST) {
    const char* hb0 = (const char*)g_hbuf + lg * 4096 + hrow2 * 16;
#pragma unroll
    for (int gq = 0; gq < 4; ++gq) {
      const char* q0 = hb0 + gq * 65536;
      u32x4 a0, a1, a2, a3;
      asm volatile(
          "global_load_dwordx4 %0, %4, off sc0\n\t"
          "global_load_dwordx4 %1, %5, off sc0\n\t"
          "global_load_dwordx4 %2, %6, off sc0\n\t"
          "global_load_dwordx4 %3, %7, off sc0\n\t"
          "s_waitcnt vmcnt(0)"
          : "=&v"(a0), "=&v"(a1), "=&v"(a2), "=&v"(a3)
          : "v"(q0), "v"(q0 + 16384), "v"(q0 + 32768), "v"(q0 + 49152)
          : "memory");
      union { u32x4 u; short8 s; } c0u = {a0}, c1u = {a1}, c2u = {a2}, c3u = {a3};
      afrag[gq * 4 + 0] = c0u.s;
      afrag[gq * 4 + 1] = c1u.s;
      afrag[gq * 4 + 2] = c2u.s;
      afrag[gq * 4 + 3] = c3u.s;
    }
  } else {
#pragma unroll
    for (int kk = 0; kk < 16; ++kk) {  // h_512 is in buffer 0
      size_t i0 = hidx(0, kk * 4 + lg, hrow2);
      unsigned long long q0 =
          __hip_atomic_load(&g_hbuf[i0], __ATOMIC_RELAXED, __HIP_MEMORY_SCOPE_AGENT);
      unsigned long long q1 =
          __hip_atomic_load(&g_hbuf[i0 + 1], __ATOMIC_RELAXED, __HIP_MEMORY_SCOPE_AGENT);
      union { unsigned long long q[2]; short8 s; } u;
      u.q[0] = q0; u.q[1] = q1;
      afrag[kk] = u.s;
    }
  }
  const int col = wi * 16 + l15;
  const float* wrow = fc_w + (size_t)col * H_ + lg * 8;
  f32x4 acc = {0.f, 0.f, 0.f, 0.f};
#pragma unroll
  for (int kk = 0; kk < 16; ++kk) {
    f32x4 a = ((const f32x4*)(wrow + kk * 32))[0];
    f32x4 b2 = ((const f32x4*)(wrow + kk * 32))[1];
    short8 bfr;
#pragma unroll
    for (int j = 0; j < 4; ++j) { bfr[j] = f2bf(a[j]); bfr[4 + j] = f2bf(b2[j]); }
    acc = __builtin_amdgcn_mfma_f32_16x16x32_bf16(afrag[kk], bfr, acc, 0, 0, 0);
  }
  const float fb = fc_b[col];
#pragma unroll
  for (int q = 0; q < 4; ++q) {
    int row_o = rb0 + lg * 4 + q;
    out[(size_t)row_o * OUT_ + col] = acc[q] + fb;
  }
}

__global__ __launch_bounds__(256, 1) void gru_persistent(
    const float* x, const float* w_ih, const float* w_hh,
    const float* bias_ih, const float* bias_hh,
    const float* fc_w, const float* fc_b, float* out) {
  const int tid = (int)threadIdx.x;
  const int w = tid >> 6;
  const int lane = tid & 63;
  const int l15 = lane & 15;
  const int lg = lane >> 4;
  const int bid = (int)blockIdx.x;
  const int cl = bid & 15;
  const int wgj = bid >> 4;
  const int rb0 = cl * BT;
  const int c0 = wgj * 64 + w * 16;
  const int wgid = cl * NWG + wgj;

  __shared__ short8 h_lds[1024];
  __shared__ short t_h[16][68];
  __shared__ int s_ok;

  // ======== semantic probe: is the sc0 store->drain->flag->load path coherent
  // across this cluster's 8 workgroups? (tests the EXACT fast-path op sequence)
  bool okl = true;
  for (int i = 0; i < 2; ++i) {
    // pre-warm this iteration's 8 sub-regions into L1 with plain loads (stale 0)
    if (tid < 128) {
      unsigned v = g_probe[(cl * NWG * 2 + (tid >> 4) * 2 + i) * 16 + (tid & 15)];
      asm volatile("" :: "v"(v));
    }
    __syncthreads();
    if (tid < 16) st_sc0(&g_probe[(wgid * 2 + i) * 16 + tid], probeval(i, wgj, tid));
    asm volatile("s_waitcnt vmcnt(0)" ::: "memory");
    __syncthreads();
    if (tid == 0) st_sc0(&g_pflag[wgid * 16], (unsigned)(i + 1));
    unsigned spins = 0;
    bool to = false;
    for (;;) {
      unsigned f = ld_sc0(&g_pflag[(cl * NWG + (lane & 7)) * 16]);
      if (__all((int)(f >= (unsigned)(i + 1)))) break;
      if (++spins > (1u << 16)) { to = true; break; }
    }
    if (to) {
      okl = false;
    } else {
      for (int j = 0; j < NWG; ++j) {
        unsigned v = ld_sc0(&g_probe[((cl * NWG + j) * 2 + i) * 16 + (tid & 15)]);
        okl = okl && (v == probeval(i, j, tid & 15));
      }
    }
  }
  if (tid == 0) s_ok = 1;
  __syncthreads();
  if (!okl) atomicAnd(&s_ok, 0);
  __syncthreads();
  const unsigned myok = (s_ok != 0) ? 1u : 0u;
  // unanimous cluster vote through the PROVEN sc1 path
  if (tid == 0)
    __hip_atomic_store(&g_vote[wgid], 0x100u | myok, __ATOMIC_RELAXED,
                       __HIP_MEMORY_SCOPE_AGENT);
  unsigned allok = 0;
  {
    unsigned spins = 0;
    for (;;) {
      unsigned got = 1;
      allok = 1;
      for (int j = 0; j < NWG; ++j) {
        unsigned vv = __hip_atomic_load(&g_vote[cl * NWG + j], __ATOMIC_RELAXED,
                                        __HIP_MEMORY_SCOPE_AGENT);
        got &= (vv >> 8) & 1u;
        allok &= vv & 1u;
      }
      if (got) break;
      __builtin_amdgcn_s_sleep(1);
      if (++spins > (1u << 24)) { allok = 0; break; }
    }
  }

  if (allok)
    run_gru<true>(x, w_ih, w_hh, bias_ih, bias_hh, fc_w, fc_b, out,
                  tid, w, lane, l15, lg, cl, wgj, rb0, c0, h_lds, t_h);
  else
    run_gru<false>(x, w_ih, w_hh, bias_ih, bias_hh, fc_w, fc_b, out,
                   tid, w, lane, l15, lg, cl, wgj, rb0, c0, h_lds, t_h);
}

extern "C" void kernel_launch(void* const* d_in, const int* in_sizes, int n_in,
                              void* d_out, int out_size, void* d_ws, size_t ws_size,
                              hipStream_t stream) {
  const float* x = (const float*)d_in[0];
  const float* w_ih = (const float*)d_in[1];
  const float* w_hh = (const float*)d_in[2];
  const float* b_ih = (const float*)d_in[3];
  const float* b_hh = (const float*)d_in[4];
  const float* fc_w = (const float*)d_in[5];
  const float* fc_b = (const float*)d_in[6];

  init_state<<<26, 256, 0, stream>>>();
  gru_persistent<<<NCL * NWG, 256, 0, stream>>>(x, w_ih, w_hh, b_ih, b_hh,
                                                fc_w, fc_b, (float*)d_out);
}

// Round 8
// 1722.799 us; speedup vs baseline: 9.1837x; 9.1837x over previous
//
#include <hip/hip_runtime.h>
#include <hip/hip_bf16.h>

#define B_ 256
#define T_ 512
#define F_ 8
#define H_ 512
#define OUT_ 96

// 16 batch-clusters x (8 workgroups x 4 waves). Each wave owns 16 h-cols
// (48 gate-cols), W slice register-resident. 128 blocks of 256 thr =>
// co-residency guaranteed by capacity. Exchange via agent-scope (L3) atomics —
// the proven round-5 protocol with poll-contention + fence cost removed.
#define NCL 16
#define BT 16
#define NWG 8

typedef __attribute__((ext_vector_type(8))) short short8;
typedef __attribute__((ext_vector_type(4))) float f32x4;

// g_hbuf: [buf][chunk=col>>3][row][2 u64]  (16B = 8 bf16 cols per (chunk,row))
__device__ unsigned long long g_hbuf[2ull * 64 * 256 * 2];
// per-cluster flag block: 8 u32 packed in ONE 64B line (single-request poll)
__device__ __align__(64) unsigned g_flag[NCL * 16];

__device__ __forceinline__ short f2bf(float v) {
  __hip_bfloat16 b = __float2bfloat16(v);
  unsigned short u;
  __builtin_memcpy(&u, &b, 2);
  return (short)u;
}

__device__ __forceinline__ size_t hidx(int buf, int chunk, int row) {
  return ((size_t)((buf * 64 + chunk) * 256 + row)) * 2;
}

__global__ void init_flags() {
  int i = blockIdx.x * 256 + (int)threadIdx.x;
  if (i < NCL * 16) g_flag[i] = 0;
}

__global__ __launch_bounds__(256, 1) void gru_persistent(
    const float* x, const float* w_ih, const float* w_hh,
    const float* bias_ih, const float* bias_hh,
    const float* fc_w, const float* fc_b, float* out) {
  const int tid = (int)threadIdx.x;
  const int w = tid >> 6;
  const int lane = tid & 63;
  const int l15 = lane & 15;
  const int lg = lane >> 4;
  const int bid = (int)blockIdx.x;
  const int cl = bid & 15;   // cluster
  const int wgj = bid >> 4;  // wg within cluster
  const int rb0 = cl * BT;
  const int c0 = wgj * 64 + w * 16;

  __shared__ short8 h_lds[1024];   // [chunk*16 + localrow], lane-linear (16 KB)
  __shared__ short t_h[16][68];    // publish transpose tile, padded stride

  // ---- W fragments, register-resident for all 512 steps ----
  short8 wfrag[3][17];
#pragma unroll
  for (int g = 0; g < 3; ++g) {
    const float* wr = w_hh + (size_t)(g * H_ + c0 + l15) * H_ + lg * 8;
#pragma unroll
    for (int kk = 0; kk < 16; ++kk) {
      f32x4 a = ((const f32x4*)(wr + kk * 32))[0];
      f32x4 b2 = ((const f32x4*)(wr + kk * 32))[1];
      short8 o;
#pragma unroll
      for (int j = 0; j < 4; ++j) { o[j] = f2bf(a[j]); o[4 + j] = f2bf(b2[j]); }
      wfrag[g][kk] = o;
    }
    short8 o = {0, 0, 0, 0, 0, 0, 0, 0};
    if (lg == 0) {  // k = 512..519 -> W_ih row
      const f32x4* wi = (const f32x4*)(w_ih + (size_t)(g * H_ + c0 + l15) * F_);
      f32x4 a = wi[0], b2 = wi[1];
#pragma unroll
      for (int j = 0; j < 4; ++j) { o[j] = f2bf(a[j]); o[4 + j] = f2bf(b2[j]); }
    }
    wfrag[g][16] = o;
  }

  const int colh = c0 + l15;
  const float b_r = bias_ih[colh] + bias_hh[colh];
  const float b_z = bias_ih[H_ + colh] + bias_hh[H_ + colh];
  const float bin_ = bias_ih[2 * H_ + colh];
  const float bhn_ = bias_hh[2 * H_ + colh];

  float hown[4] = {0.f, 0.f, 0.f, 0.f};
  bool gaveup = false;

  const int hrow = rb0 + l15;
  const float* xrow = x + (size_t)hrow * T_ * F_;

  // x prefetch for t=0
  f32x4 xa = ((const f32x4*)xrow)[0];
  f32x4 xb2 = ((const f32x4*)xrow)[1];

  for (int t = 0; t < T_; ++t) {
    if (t > 0) {
      // ---- poll: ONE coalesced load per wave per iteration, __all exit ----
      if (!gaveup) {
        unsigned spins = 0;
        for (;;) {
          unsigned f = __hip_atomic_load(&g_flag[cl * 16 + (lane & 7)],
                                         __ATOMIC_RELAXED, __HIP_MEMORY_SCOPE_AGENT);
          if (__all((int)(f >= (unsigned)t))) break;
          __builtin_amdgcn_s_sleep(2);
          if (++spins > (1u << 20)) { gaveup = true; break; }
        }
        // No acquire fence: gather uses agent-scope atomic loads reaching the
        // same coherence point (L3). Producer drains stores (vmcnt0) before its
        // flag store; we issue gathers only after observing the flag. The
        // sched_barrier pins compiler ordering at zero runtime cost.
        __builtin_amdgcn_sched_barrier(0);
      }
      // ---- cooperative gather, lane-linear (conflict-free LDS writes) ----
      const int buf = t & 1;
#pragma unroll
      for (int r4 = 0; r4 < 4; ++r4) {
        const int idx = r4 * 256 + tid;     // 0..1023
        const int chunk = idx >> 4;
        const int lr = idx & 15;
        size_t i0 = hidx(buf, chunk, rb0 + lr);
        unsigned long long q0 = __hip_atomic_load(&g_hbuf[i0], __ATOMIC_RELAXED,
                                                  __HIP_MEMORY_SCOPE_AGENT);
        unsigned long long q1 = __hip_atomic_load(&g_hbuf[i0 + 1], __ATOMIC_RELAXED,
                                                  __HIP_MEMORY_SCOPE_AGENT);
        union { unsigned long long q[2]; short8 s; } u;
        u.q[0] = q0; u.q[1] = q1;
        h_lds[idx] = u.s;
      }
    }

    // x fragment from prefetched registers
    short8 xf;
#pragma unroll
    for (int j = 0; j < 4; ++j) { xf[j] = f2bf(xa[j]); xf[4 + j] = f2bf(xb2[j]); }

    __syncthreads();  // h_lds ready

    // prefetch x for t+1 (stays cached — no more per-step L2 invalidate)
    {
      const int tn = (t + 1 < T_) ? t + 1 : T_ - 1;
      xa = ((const f32x4*)(xrow + (size_t)tn * F_))[0];
      xb2 = ((const f32x4*)(xrow + (size_t)tn * F_))[1];
    }

    // ---- MFMAs: 3 gates per kk (short afrag live range, 3 indep acc chains) ----
    f32x4 acc_r = {0.f, 0.f, 0.f, 0.f}, acc_z = {0.f, 0.f, 0.f, 0.f};
    f32x4 acc_nh = {0.f, 0.f, 0.f, 0.f}, acc_nx = {0.f, 0.f, 0.f, 0.f};
    if (t > 0) {
#pragma unroll
      for (int kk = 0; kk < 16; ++kk) {
        short8 a = h_lds[(kk * 4 + lg) * 16 + l15];
        acc_r = __builtin_amdgcn_mfma_f32_16x16x32_bf16(a, wfrag[0][kk], acc_r, 0, 0, 0);
        acc_z = __builtin_amdgcn_mfma_f32_16x16x32_bf16(a, wfrag[1][kk], acc_z, 0, 0, 0);
        acc_nh = __builtin_amdgcn_mfma_f32_16x16x32_bf16(a, wfrag[2][kk], acc_nh, 0, 0, 0);
      }
    }
    acc_r = __builtin_amdgcn_mfma_f32_16x16x32_bf16(xf, wfrag[0][16], acc_r, 0, 0, 0);
    acc_z = __builtin_amdgcn_mfma_f32_16x16x32_bf16(xf, wfrag[1][16], acc_z, 0, 0, 0);
    acc_nx = __builtin_amdgcn_mfma_f32_16x16x32_bf16(xf, wfrag[2][16], acc_nx, 0, 0, 0);

    // ---- gates + fp32-carry state update ----
    short hnew[4];
#pragma unroll
    for (int q = 0; q < 4; ++q) {
      float pr = acc_r[q] + b_r;
      float pz = acc_z[q] + b_z;
      float r = 1.f / (1.f + __expf(-pr));
      float z = 1.f / (1.f + __expf(-pz));
      float n = tanhf(acc_nx[q] + bin_ + r * (acc_nh[q] + bhn_));
      hown[q] = n + z * (hown[q] - n);
      hnew[q] = f2bf(hown[q]);
    }

    // ---- publish via padded LDS transpose -> one aligned u64 sc1 store/lane ----
#pragma unroll
    for (int q = 0; q < 4; ++q) t_h[4 * lg + q][w * 16 + l15] = hnew[q];
    __syncthreads();  // tile complete
    {
      const int row_l = tid >> 4;
      const int ucol = tid & 15;
      const int col = wgj * 64 + ucol * 4;
      const int grow = rb0 + row_l;
      unsigned long long v;
      __builtin_memcpy(&v, &t_h[row_l][ucol * 4], 8);
      size_t i0 = hidx((t + 1) & 1, col >> 3, grow) + ((col >> 2) & 1);
      __hip_atomic_store(&g_hbuf[i0], v, __ATOMIC_RELAXED, __HIP_MEMORY_SCOPE_AGENT);
    }
    __syncthreads();  // vmcnt(0) drain: all 4 waves' stores at coherence point
    if (tid == 0)     // release: relaxed store into the packed cluster line
      __hip_atomic_store(&g_flag[cl * 16 + wgj], (unsigned)(t + 1),
                         __ATOMIC_RELAXED, __HIP_MEMORY_SCOPE_AGENT);
  }

  // ---- final FC: 6 waves per cluster cover the 96 output columns ----
  const int wi = wgj * 4 + w;
  if (wi >= OUT_ / 16) return;
  if (!gaveup) {
    unsigned spins = 0;
    for (;;) {
      unsigned f = __hip_atomic_load(&g_flag[cl * 16 + (lane & 7)],
                                     __ATOMIC_RELAXED, __HIP_MEMORY_SCOPE_AGENT);
      if (__all((int)(f >= (unsigned)T_))) break;
      __builtin_amdgcn_s_sleep(2);
      if (++spins > (1u << 20)) break;
    }
    __builtin_amdgcn_fence(__ATOMIC_ACQUIRE, "agent");  // once, cheap
  }
  short8 afrag[16];
#pragma unroll
  for (int kk = 0; kk < 16; ++kk) {  // h_512 is in buffer (512 & 1) == 0
    size_t i0 = hidx(0, kk * 4 + lg, hrow);
    unsigned long long q0 =
        __hip_atomic_load(&g_hbuf[i0], __ATOMIC_RELAXED, __HIP_MEMORY_SCOPE_AGENT);
    unsigned long long q1 =
        __hip_atomic_load(&g_hbuf[i0 + 1], __ATOMIC_RELAXED, __HIP_MEMORY_SCOPE_AGENT);
    union { unsigned long long q[2]; short8 s; } u;
    u.q[0] = q0; u.q[1] = q1;
    afrag[kk] = u.s;
  }
  const int col = wi * 16 + l15;
  const float* wrow = fc_w + (size_t)col * H_ + lg * 8;
  f32x4 acc = {0.f, 0.f, 0.f, 0.f};
#pragma unroll
  for (int kk = 0; kk < 16; ++kk) {
    f32x4 a = ((const f32x4*)(wrow + kk * 32))[0];
    f32x4 b2 = ((const f32x4*)(wrow + kk * 32))[1];
    short8 bfr;
#pragma unroll
    for (int j = 0; j < 4; ++j) { bfr[j] = f2bf(a[j]); bfr[4 + j] = f2bf(b2[j]); }
    acc = __builtin_amdgcn_mfma_f32_16x16x32_bf16(afrag[kk], bfr, acc, 0, 0, 0);
  }
  const float fb = fc_b[col];
#pragma unroll
  for (int q = 0; q < 4; ++q) {
    int row_o = rb0 + lg * 4 + q;
    out[(size_t)row_o * OUT_ + col] = acc[q] + fb;
  }
}

extern "C" void kernel_launch(void* const* d_in, const int* in_sizes, int n_in,
                              void* d_out, int out_size, void* d_ws, size_t ws_size,
                              hipStream_t stream) {
  const float* x = (const float*)d_in[0];
  const float* w_ih = (const float*)d_in[1];
  const float* w_hh = (const float*)d_in[2];
  const float* b_ih = (const float*)d_in[3];
  const float* b_hh = (const float*)d_in[4];
  const float* fc_w = (const float*)d_in[5];
  const float* fc_b = (const float*)d_in[6];

  init_flags<<<1, 256, 0, stream>>>();
  gru_persistent<<<NCL * NWG, 256, 0, stream>>>(x, w_ih, w_hh, b_ih, b_hh,
                                                fc_w, fc_b, (float*)d_out);
}